// Round 1
// baseline (485.767 us; speedup 1.0000x reference)
//
#include <hip/hip_runtime.h>
#include <hip/hip_bf16.h>

// Problem constants (DeformableConv2DLayer: B=4, Cin=64, H=W=128, Cout=64,
// 3x3, stride=1, pad=1, dil=1, DG=1)
#define B_  4
#define CIN 64
#define HH  128
#define WW  128
#define COUT 64
#define KK  9   // 3x3

// ---------------------------------------------------------------------------
// Kernel 1: transpose main conv weight [Cout][Cin][3][3] -> wt[Cin*9][Cout]
// so that per-(c,k) weight rows are contiguous and lane-uniform (s_loads).
// ---------------------------------------------------------------------------
__global__ void transpose_w_kernel(const float* __restrict__ w,
                                   float* __restrict__ wt) {
    int i = blockIdx.x * 256 + threadIdx.x;              // over 64*64*9 = 36864
    if (i >= COUT * CIN * KK) return;
    int o = i / (CIN * KK);
    int r = i - o * (CIN * KK);                           // c*9 + k
    wt[r * COUT + o] = w[i];
}

// ---------------------------------------------------------------------------
// Kernel 2: offset/mask conv. One block per (b, ho) row, 128 threads = wo.
// Stages 3 input rows (with halo) per input channel in LDS.
// Output om[b][27][H][W]; channels 18..26 get sigmoid applied.
// ---------------------------------------------------------------------------
__global__ __launch_bounds__(128, 2)
void offset_conv_kernel(const float* __restrict__ x,
                        const float* __restrict__ ow,
                        const float* __restrict__ ob,
                        float* __restrict__ om) {
    int bh = blockIdx.x;                 // b*128 + ho
    int b  = bh >> 7;
    int ho = bh & 127;
    int wo = threadIdx.x;                // 0..127

    __shared__ float rows[3][WW + 2];

    float acc[27];
#pragma unroll
    for (int oc = 0; oc < 27; ++oc) acc[oc] = 0.f;

    const float* xb = x + (size_t)b * CIN * HH * WW;

    for (int c = 0; c < CIN; ++c) {
        const float* xc = xb + (size_t)c * HH * WW;
        __syncthreads();
#pragma unroll
        for (int r = 0; r < 3; ++r) {
            int hh = ho - 1 + r;
            float v = 0.f;
            if (hh >= 0 && hh < HH) v = xc[hh * WW + wo];
            rows[r][wo + 1] = v;
            if (wo == 0) { rows[r][0] = 0.f; rows[r][WW + 1] = 0.f; }
        }
        __syncthreads();

        float v[9];
#pragma unroll
        for (int ki = 0; ki < 3; ++ki)
#pragma unroll
            for (int kj = 0; kj < 3; ++kj)
                v[ki * 3 + kj] = rows[ki][wo + kj];

        const float* wc = ow + c * KK;   // + oc * (CIN*KK)
#pragma unroll
        for (int oc = 0; oc < 27; ++oc) {
#pragma unroll
            for (int t = 0; t < 9; ++t)
                acc[oc] += v[t] * wc[oc * (CIN * KK) + t];
        }
    }

    float* omp = om + (((size_t)b * 27) * HH + ho) * WW + wo;
#pragma unroll
    for (int oc = 0; oc < 27; ++oc) {
        float r = acc[oc] + ob[oc];
        if (oc >= 18) r = 1.f / (1.f + __expf(-r));   // sigmoid on mask chans
        omp[(size_t)oc * HH * WW] = r;
    }
}

// ---------------------------------------------------------------------------
// Kernel 3: deformable aggregation + 64x576 per-pixel matmul.
// One block per (b, ho) row; 256 threads: wo = t&127, half = t>>7 (32 Cout).
// Per-thread precomputed clamped corner indices and premultiplied bilinear
// weights (validity- and mask-scaled). Inner loop: 4 cached global loads +
// 4 FMA (bilinear) + 32 FMA vs scalar weights per (c,k).
// ---------------------------------------------------------------------------
__global__ __launch_bounds__(256, 2)
void dcn_main_kernel(const float* __restrict__ x,
                     const float* __restrict__ wt,   // [Cin*9][Cout]
                     const float* __restrict__ bias,
                     const float* __restrict__ om,   // [B][27][H][W]
                     float* __restrict__ out) {
    int bh = blockIdx.x;                 // b*128 + ho
    int b  = bh >> 7;
    int ho = bh & 127;
    int wo = threadIdx.x & 127;
    int oh = __builtin_amdgcn_readfirstlane(threadIdx.x >> 7);  // 0 or 1

    const float* omp = om + (((size_t)b * 27) * HH + ho) * WW + wo;

    int   cidx[9][4];
    float cwt [9][4];
#pragma unroll
    for (int k = 0; k < 9; ++k) {
        float dy = omp[(size_t)k        * HH * WW];
        float dx = omp[(size_t)(9 + k)  * HH * WW];
        float mk = omp[(size_t)(18 + k) * HH * WW];
        float hf = (float)(ho - 1 + k / 3) + dy;
        float wf = (float)(wo - 1 + k % 3) + dx;
        float h0f = floorf(hf), w0f = floorf(wf);
        float lh = hf - h0f, lw = wf - w0f;
        int h0 = (int)h0f, w0 = (int)w0f;
        int h1 = h0 + 1,   w1 = w0 + 1;
        bool vh0 = (h0 >= 0) && (h0 < HH);
        bool vh1 = (h1 >= 0) && (h1 < HH);
        bool vw0 = (w0 >= 0) && (w0 < WW);
        bool vw1 = (w1 >= 0) && (w1 < WW);
        int ch0 = min(max(h0, 0), HH - 1), ch1 = min(max(h1, 0), HH - 1);
        int cw0 = min(max(w0, 0), WW - 1), cw1 = min(max(w1, 0), WW - 1);
        cidx[k][0] = ch0 * WW + cw0;
        cidx[k][1] = ch0 * WW + cw1;
        cidx[k][2] = ch1 * WW + cw0;
        cidx[k][3] = ch1 * WW + cw1;
        cwt[k][0] = (vh0 && vw0) ? (1.f - lh) * (1.f - lw) * mk : 0.f;
        cwt[k][1] = (vh0 && vw1) ? (1.f - lh) * lw         * mk : 0.f;
        cwt[k][2] = (vh1 && vw0) ? lh         * (1.f - lw) * mk : 0.f;
        cwt[k][3] = (vh1 && vw1) ? lh         * lw         * mk : 0.f;
    }

    float acc[32];
#pragma unroll
    for (int o = 0; o < 32; ++o) acc[o] = 0.f;

    const float* xb  = x + (size_t)b * CIN * HH * WW;
    const float* wto = wt + oh * 32;

    for (int c = 0; c < CIN; ++c) {
        const float* xc = xb + (size_t)c * HH * WW;
#pragma unroll
        for (int k = 0; k < 9; ++k) {
            float v = cwt[k][0] * xc[cidx[k][0]]
                    + cwt[k][1] * xc[cidx[k][1]]
                    + cwt[k][2] * xc[cidx[k][2]]
                    + cwt[k][3] * xc[cidx[k][3]];
            const float* wrow = wto + (c * 9 + k) * COUT;   // lane-uniform
#pragma unroll
            for (int o = 0; o < 32; ++o)
                acc[o] += v * wrow[o];
        }
    }

    float* op = out + ((((size_t)b * COUT) + oh * 32) * HH + ho) * WW + wo;
#pragma unroll
    for (int o = 0; o < 32; ++o)
        op[(size_t)o * HH * WW] = acc[o] + bias[oh * 32 + o];
}

// ---------------------------------------------------------------------------
extern "C" void kernel_launch(void* const* d_in, const int* in_sizes, int n_in,
                              void* d_out, int out_size, void* d_ws, size_t ws_size,
                              hipStream_t stream) {
    const float* x    = (const float*)d_in[0];
    const float* wgt  = (const float*)d_in[1];
    const float* bias = (const float*)d_in[2];
    const float* ow   = (const float*)d_in[3];
    const float* ob   = (const float*)d_in[4];
    float* out = (float*)d_out;

    // workspace layout: wt [Cin*9*Cout] then om [B*27*H*W]
    float* wt = (float*)d_ws;
    float* om = wt + (size_t)CIN * KK * COUT;   // 36864 floats

    transpose_w_kernel<<<(COUT * CIN * KK + 255) / 256, 256, 0, stream>>>(wgt, wt);
    offset_conv_kernel<<<B_ * HH, 128, 0, stream>>>(x, ow, ob, om);
    dcn_main_kernel<<<B_ * HH, 256, 0, stream>>>(x, wt, bias, om, out);
}